// Round 1
// baseline (1558.254 us; speedup 1.0000x reference)
//
#include <hip/hip_runtime.h>
#include <hip/hip_bf16.h>

#define NN 50000
#define NE 800000
#define DIM 128

// K0: fold W into the attention vectors: v1 = a1^T W, v2 = a2^T W, c1 = b.a1, c2 = b.a2
__global__ void k_prep(const float* __restrict__ W, const float* __restrict__ wb,
                       const float* __restrict__ aw, float* __restrict__ v12c){
  int k = threadIdx.x;                       // 0..127
  float s1 = 0.f, s2 = 0.f;
  for (int j = 0; j < DIM; ++j){
    float w = W[j*DIM + k];                  // column k of W, coalesced across threads
    s1 += aw[j] * w;
    s2 += aw[DIM + j] * w;
  }
  v12c[k] = s1;
  v12c[DIM + k] = s2;
  __shared__ float r1[DIM], r2[DIM];
  float b = wb[k];
  r1[k] = b * aw[k];
  r2[k] = b * aw[DIM + k];
  __syncthreads();
  for (int off = 64; off > 0; off >>= 1){
    if (k < off){ r1[k] += r1[k+off]; r2[k] += r2[k+off]; }
    __syncthreads();
  }
  if (k == 0){ v12c[2*DIM] = r1[0]; v12c[2*DIM+1] = r2[0]; }
}

// K1: p1[i] = emb[i].v1 + c1 ; p2[i] = emb[i].v2 + c2. One 32-lane group per node.
__global__ __launch_bounds__(256) void k_pvec(const float4* __restrict__ emb4,
                      const float* __restrict__ v12c,
                      float* __restrict__ p1, float* __restrict__ p2){
  int g = threadIdx.x & 31;
  int i = blockIdx.x * 8 + (threadIdx.x >> 5);
  if (i >= NN) return;
  float4 e = emb4[i*32 + g];
  float4 a = ((const float4*)v12c)[g];
  float4 b = ((const float4*)v12c)[32 + g];
  float s1 = e.x*a.x + e.y*a.y + e.z*a.z + e.w*a.w;
  float s2 = e.x*b.x + e.y*b.y + e.z*b.z + e.w*b.w;
  #pragma unroll
  for (int off = 16; off; off >>= 1){
    s1 += __shfl_down(s1, off, 32);
    s2 += __shfl_down(s2, off, 32);
  }
  if (g == 0){
    p1[i] = s1 + v12c[256];
    p2[i] = s2 + v12c[257];
  }
}

// K2: per edge: attn = exp(leaky_relu(p1[d]+p2[s]+ab)); denom[d] += attn;
//     agg[d][:] += attn * emb[s][:].  32 lanes per edge, float4 per lane.
__global__ __launch_bounds__(256) void k_edge(const int* __restrict__ dst, const int* __restrict__ src,
                      const float* __restrict__ p1, const float* __restrict__ p2,
                      const float* __restrict__ abias,
                      const float4* __restrict__ emb4,
                      float* __restrict__ denom, float* __restrict__ agg){
  int g = threadIdx.x & 31;
  int e = blockIdx.x * 8 + (threadIdx.x >> 5);
  if (e >= NE) return;
  int d = dst[e];
  int s = src[e];
  float attn = 0.f;
  if (g == 0){
    float sc = p1[d] + p2[s] + abias[0];
    sc = sc > 0.f ? sc : 0.2f * sc;
    attn = __expf(sc);
    unsafeAtomicAdd(&denom[d], attn);   // HW global_atomic_add_f32
  }
  attn = __shfl(attn, 0, 32);
  float4 v = emb4[s*32 + g];
  float* ap = agg + d*DIM + g*4;
  unsafeAtomicAdd(ap + 0, attn * v.x);
  unsafeAtomicAdd(ap + 1, attn * v.y);
  unsafeAtomicAdd(ap + 2, attn * v.z);
  unsafeAtomicAdd(ap + 3, attn * v.w);
}

// K3: h = [emb, agg/denom] @ T^T + tb, then LayerNorm. 32 nodes x 128 cols per block.
// Thread (c = t&31, r = t>>5) computes cols 4c..4c+3 of nodes {r, r+8, r+16, r+24}.
// T staged transposed in LDS so compute reads are float4-contiguous.
__global__ __launch_bounds__(256) void k_out(const float4* __restrict__ emb4,
                     const float4* __restrict__ agg4, const float* __restrict__ denom,
                     const float4* __restrict__ T4, const float* __restrict__ tb,
                     const float* __restrict__ gamma, const float* __restrict__ beta,
                     float4* __restrict__ out4){
  __shared__ float As[32][33];    // [kk][local_node], +1 pad
  __shared__ float Ts[32][132];   // [kk][j], width 132: 16B-aligned rows, pad vs bank stride
  int t = threadIdx.x;
  int base = blockIdx.x * 32;
  int c = t & 31;
  int r = t >> 5;
  float acc[4][4] = {};
  int a_node = t >> 3;            // staging: local node 0..31
  int a_q = t & 7;                // staging: float4 index within 32-wide k-chunk
  int gnode = base + a_node;
  float dv = (gnode < NN) ? denom[gnode] : 0.f;
  float dinv = 1.0f / (dv + 1e-20f);

  for (int kc = 0; kc < 8; ++kc){
    float4 av = make_float4(0.f, 0.f, 0.f, 0.f);
    if (gnode < NN){
      if (kc < 4){
        av = emb4[gnode*32 + kc*8 + a_q];
      } else {
        av = agg4[gnode*32 + (kc-4)*8 + a_q];
        av.x *= dinv; av.y *= dinv; av.z *= dinv; av.w *= dinv;
      }
    }
    As[a_q*4+0][a_node] = av.x;
    As[a_q*4+1][a_node] = av.y;
    As[a_q*4+2][a_node] = av.z;
    As[a_q*4+3][a_node] = av.w;
    #pragma unroll
    for (int i2 = 0; i2 < 4; ++i2){
      int f = t + 256*i2;
      int j = f >> 3, q = f & 7;
      float4 tv = T4[j*64 + kc*8 + q];   // T row j, k-chunk kc, coalesced along k
      Ts[q*4+0][j] = tv.x;
      Ts[q*4+1][j] = tv.y;
      Ts[q*4+2][j] = tv.z;
      Ts[q*4+3][j] = tv.w;
    }
    __syncthreads();
    #pragma unroll
    for (int kk = 0; kk < 32; ++kk){
      float4 tv = *(const float4*)&Ts[kk][c*4];            // b128, conflict-free
      float a0 = As[kk][r], a1 = As[kk][r+8], a2 = As[kk][r+16], a3 = As[kk][r+24]; // broadcast
      acc[0][0] += a0*tv.x; acc[0][1] += a0*tv.y; acc[0][2] += a0*tv.z; acc[0][3] += a0*tv.w;
      acc[1][0] += a1*tv.x; acc[1][1] += a1*tv.y; acc[1][2] += a1*tv.z; acc[1][3] += a1*tv.w;
      acc[2][0] += a2*tv.x; acc[2][1] += a2*tv.y; acc[2][2] += a2*tv.z; acc[2][3] += a2*tv.w;
      acc[3][0] += a3*tv.x; acc[3][1] += a3*tv.y; acc[3][2] += a3*tv.z; acc[3][3] += a3*tv.w;
    }
    __syncthreads();
  }
  float tb0 = tb[c*4+0], tb1 = tb[c*4+1], tb2 = tb[c*4+2], tb3 = tb[c*4+3];
  float gm0 = gamma[c*4+0], gm1 = gamma[c*4+1], gm2 = gamma[c*4+2], gm3 = gamma[c*4+3];
  float bt0 = beta[c*4+0], bt1 = beta[c*4+1], bt2 = beta[c*4+2], bt3 = beta[c*4+3];
  #pragma unroll
  for (int m = 0; m < 4; ++m){
    int n = base + r + 8*m;
    float h0 = acc[m][0] + tb0;
    float h1 = acc[m][1] + tb1;
    float h2 = acc[m][2] + tb2;
    float h3 = acc[m][3] + tb3;
    float s  = h0 + h1 + h2 + h3;
    float ss = h0*h0 + h1*h1 + h2*h2 + h3*h3;
    // node n's 128 cols live in 32 contiguous lanes (one half-wave): butterfly over width 32
    #pragma unroll
    for (int off = 16; off; off >>= 1){
      s  += __shfl_xor(s,  off, 32);
      ss += __shfl_xor(ss, off, 32);
    }
    float mu = s * (1.f/128.f);
    float var = ss * (1.f/128.f) - mu*mu;
    float rstd = rsqrtf(var + 1e-5f);
    if (n < NN){
      out4[n*32 + c] = make_float4((h0-mu)*rstd*gm0 + bt0,
                                   (h1-mu)*rstd*gm1 + bt1,
                                   (h2-mu)*rstd*gm2 + bt2,
                                   (h3-mu)*rstd*gm3 + bt3);
    }
  }
}

extern "C" void kernel_launch(void* const* d_in, const int* in_sizes, int n_in,
                              void* d_out, int out_size, void* d_ws, size_t ws_size,
                              hipStream_t stream){
  const float* emb          = (const float*)d_in[0];
  const int*   edges        = (const int*)d_in[1];
  const float* w_weight     = (const float*)d_in[2];
  const float* w_bias       = (const float*)d_in[3];
  const float* a_weight     = (const float*)d_in[4];
  const float* a_bias       = (const float*)d_in[5];
  const float* trans_weight = (const float*)d_in[6];
  const float* trans_bias   = (const float*)d_in[7];
  const float* ln_gamma     = (const float*)d_in[8];
  const float* ln_beta      = (const float*)d_in[9];
  float* out = (float*)d_out;

  // workspace layout (floats): agg[6.4M] | denom[50k] | p1[50k] | p2[50k] | v12c[258]
  float* ws    = (float*)d_ws;
  float* agg   = ws;
  float* denom = ws + 6400000;
  float* p1    = ws + 6450000;
  float* p2    = ws + 6500000;
  float* v12c  = ws + 6550000;

  hipMemsetAsync(agg, 0, (6400000 + 50000) * sizeof(float), stream);  // zero agg + denom
  k_prep<<<1, 128, 0, stream>>>(w_weight, w_bias, a_weight, v12c);
  k_pvec<<<(NN + 7)/8, 256, 0, stream>>>((const float4*)emb, v12c, p1, p2);
  k_edge<<<(NE + 7)/8, 256, 0, stream>>>(edges, edges + NE, p1, p2, a_bias,
                                         (const float4*)emb, denom, agg);
  k_out<<<(NN + 31)/32, 256, 0, stream>>>((const float4*)emb, (const float4*)agg, denom,
                                          (const float4*)trans_weight, trans_bias,
                                          ln_gamma, ln_beta, (float4*)out);
}

// Round 2
// 320.131 us; speedup vs baseline: 4.8676x; 4.8676x over previous
//
#include <hip/hip_runtime.h>
#include <hip/hip_bf16.h>

#define NN 50000
#define NE 800000
#define DIM 128
#define SCAN_BLK 49   // ceil(50000/1024)

// K0: fold W into attention vectors: v1 = a1^T W, v2 = a2^T W,
// c1 = b.a1 + a_bias (a_bias folded so score = p1[d] + p2[s]), c2 = b.a2
__global__ void k_prep(const float* __restrict__ W, const float* __restrict__ wb,
                       const float* __restrict__ aw, const float* __restrict__ ab,
                       float* __restrict__ v12c){
  int k = threadIdx.x;                       // 0..127
  float s1 = 0.f, s2 = 0.f;
  for (int j = 0; j < DIM; ++j){
    float w = W[j*DIM + k];                  // column k of W, coalesced
    s1 += aw[j] * w;
    s2 += aw[DIM + j] * w;
  }
  v12c[k] = s1;
  v12c[DIM + k] = s2;
  __shared__ float r1[DIM], r2[DIM];
  float b = wb[k];
  r1[k] = b * aw[k];
  r2[k] = b * aw[DIM + k];
  __syncthreads();
  for (int off = 64; off > 0; off >>= 1){
    if (k < off){ r1[k] += r1[k+off]; r2[k] += r2[k+off]; }
    __syncthreads();
  }
  if (k == 0){ v12c[2*DIM] = r1[0] + ab[0]; v12c[2*DIM+1] = r2[0]; }
}

// K1: p1[i] = emb[i].v1 + c1 ; p2[i] = emb[i].v2 + c2. 32 lanes per node.
__global__ __launch_bounds__(256) void k_pvec(const float4* __restrict__ emb4,
                      const float* __restrict__ v12c,
                      float* __restrict__ p1, float* __restrict__ p2){
  int g = threadIdx.x & 31;
  int i = blockIdx.x * 8 + (threadIdx.x >> 5);
  if (i >= NN) return;
  float4 e = emb4[i*32 + g];
  float4 a = ((const float4*)v12c)[g];
  float4 b = ((const float4*)v12c)[32 + g];
  float s1 = e.x*a.x + e.y*a.y + e.z*a.z + e.w*a.w;
  float s2 = e.x*b.x + e.y*b.y + e.z*b.z + e.w*b.w;
  #pragma unroll
  for (int off = 16; off; off >>= 1){
    s1 += __shfl_down(s1, off, 32);
    s2 += __shfl_down(s2, off, 32);
  }
  if (g == 0){
    p1[i] = s1 + v12c[256];
    p2[i] = s2 + v12c[257];
  }
}

// K2: histogram of destination degrees (int atomics — HW-fast)
__global__ __launch_bounds__(256) void k_hist(const int* __restrict__ dst, int* __restrict__ count){
  int e = blockIdx.x * 256 + threadIdx.x;
  if (e < NE) atomicAdd(&count[dst[e]], 1);
}

// K3a: per-1024-block exclusive scan of counts; block totals to bsum
__global__ __launch_bounds__(1024) void k_scanA(const int* __restrict__ count,
                                                int* __restrict__ rowptr, int* __restrict__ bsum){
  __shared__ int sm[1024];
  int t = threadIdx.x;
  int i = blockIdx.x * 1024 + t;
  int c = (i < NN) ? count[i] : 0;
  sm[t] = c;
  __syncthreads();
  for (int off = 1; off < 1024; off <<= 1){
    int add = (t >= off) ? sm[t-off] : 0;
    __syncthreads();
    sm[t] += add;
    __syncthreads();
  }
  if (i < NN) rowptr[i] = sm[t] - c;          // exclusive within block
  if (t == 1023) bsum[blockIdx.x] = sm[t];
}

// K3b: scan the 49 block sums (single wave)
__global__ void k_scanB(const int* __restrict__ bsum, int* __restrict__ boff){
  int t = threadIdx.x;
  int v = (t < SCAN_BLK) ? bsum[t] : 0;
  int incl = v;
  #pragma unroll
  for (int off = 1; off < 64; off <<= 1){
    int u = __shfl_up(incl, off, 64);
    if (t >= off) incl += u;
  }
  if (t < SCAN_BLK) boff[t] = incl - v;
}

// K3c: add block offsets; set rowptr[NN]
__global__ __launch_bounds__(256) void k_scanC(int* __restrict__ rowptr, const int* __restrict__ boff){
  int i = blockIdx.x * 256 + threadIdx.x;
  if (i < NN) rowptr[i] += boff[i >> 10];
  if (i == 0) rowptr[NN] = NE;
}

// K4: scatter edges into CSR order; precompute attn per edge.
__global__ __launch_bounds__(256) void k_scatter(const int* __restrict__ dst, const int* __restrict__ src,
                        const float* __restrict__ p1, const float* __restrict__ p2,
                        const int* __restrict__ rowptr, int* __restrict__ cursor,
                        int* __restrict__ csr_src, float* __restrict__ csr_attn){
  int e = blockIdx.x * 256 + threadIdx.x;
  if (e >= NE) return;
  int d = dst[e];
  int s = src[e];
  float sc = p1[d] + p2[s];                 // a_bias already folded into p1
  sc = sc > 0.f ? sc : 0.2f * sc;
  float a = __expf(sc);
  int pos = rowptr[d] + atomicAdd(&cursor[d], 1);
  csr_src[pos] = s;
  csr_attn[pos] = a;
}

// K5: one 64-lane wave per destination node; accumulate agg row in registers,
// 2 edges in flight (one per 32-lane half), normalize by denom in-wave, single store.
__global__ __launch_bounds__(256) void k_gather(const int* __restrict__ rowptr,
                       const int* __restrict__ csr_src, const float* __restrict__ csr_attn,
                       const float4* __restrict__ emb4, float4* __restrict__ agg4){
  int lane = threadIdx.x & 63;
  int g = lane & 31;
  int h = lane >> 5;
  int n = blockIdx.x * 4 + (threadIdx.x >> 6);
  if (n >= NN) return;
  int s0 = rowptr[n], s1 = rowptr[n+1];
  float4 acc = make_float4(0.f, 0.f, 0.f, 0.f);
  float dsum = 0.f;
  for (int e = s0 + h; e < s1; e += 2){
    int s = csr_src[e];                     // broadcast within half-wave
    float a = csr_attn[e];
    dsum += a;
    float4 v = emb4[s*32 + g];              // 512B coalesced per half-wave
    acc.x += a*v.x; acc.y += a*v.y; acc.z += a*v.z; acc.w += a*v.w;
  }
  // combine the two halves
  acc.x += __shfl_xor(acc.x, 32, 64);
  acc.y += __shfl_xor(acc.y, 32, 64);
  acc.z += __shfl_xor(acc.z, 32, 64);
  acc.w += __shfl_xor(acc.w, 32, 64);
  dsum  += __shfl_xor(dsum, 32, 64);
  if (h == 0){
    float dinv = 1.0f / (dsum + 1e-20f);
    agg4[n*32 + g] = make_float4(acc.x*dinv, acc.y*dinv, acc.z*dinv, acc.w*dinv);
  }
}

// K6: h = [emb, agg] @ T^T + tb, then LayerNorm. 32 nodes x 128 cols per block.
__global__ __launch_bounds__(256) void k_out(const float4* __restrict__ emb4,
                     const float4* __restrict__ agg4,
                     const float4* __restrict__ T4, const float* __restrict__ tb,
                     const float* __restrict__ gamma, const float* __restrict__ beta,
                     float4* __restrict__ out4){
  __shared__ float As[32][33];    // [kk][local_node], +1 pad
  __shared__ float Ts[32][132];   // [kk][j]
  int t = threadIdx.x;
  int base = blockIdx.x * 32;
  int c = t & 31;
  int r = t >> 5;
  float acc[4][4] = {};
  int a_node = t >> 3;
  int a_q = t & 7;
  int gnode = base + a_node;

  for (int kc = 0; kc < 8; ++kc){
    float4 av = make_float4(0.f, 0.f, 0.f, 0.f);
    if (gnode < NN){
      av = (kc < 4) ? emb4[gnode*32 + kc*8 + a_q]
                    : agg4[gnode*32 + (kc-4)*8 + a_q];
    }
    As[a_q*4+0][a_node] = av.x;
    As[a_q*4+1][a_node] = av.y;
    As[a_q*4+2][a_node] = av.z;
    As[a_q*4+3][a_node] = av.w;
    #pragma unroll
    for (int i2 = 0; i2 < 4; ++i2){
      int f = t + 256*i2;
      int j = f >> 3, q = f & 7;
      float4 tv = T4[j*64 + kc*8 + q];
      Ts[q*4+0][j] = tv.x;
      Ts[q*4+1][j] = tv.y;
      Ts[q*4+2][j] = tv.z;
      Ts[q*4+3][j] = tv.w;
    }
    __syncthreads();
    #pragma unroll
    for (int kk = 0; kk < 32; ++kk){
      float4 tv = *(const float4*)&Ts[kk][c*4];
      float a0 = As[kk][r], a1 = As[kk][r+8], a2 = As[kk][r+16], a3 = As[kk][r+24];
      acc[0][0] += a0*tv.x; acc[0][1] += a0*tv.y; acc[0][2] += a0*tv.z; acc[0][3] += a0*tv.w;
      acc[1][0] += a1*tv.x; acc[1][1] += a1*tv.y; acc[1][2] += a1*tv.z; acc[1][3] += a1*tv.w;
      acc[2][0] += a2*tv.x; acc[2][1] += a2*tv.y; acc[2][2] += a2*tv.z; acc[2][3] += a2*tv.w;
      acc[3][0] += a3*tv.x; acc[3][1] += a3*tv.y; acc[3][2] += a3*tv.z; acc[3][3] += a3*tv.w;
    }
    __syncthreads();
  }
  float tb0 = tb[c*4+0], tb1 = tb[c*4+1], tb2 = tb[c*4+2], tb3 = tb[c*4+3];
  float gm0 = gamma[c*4+0], gm1 = gamma[c*4+1], gm2 = gamma[c*4+2], gm3 = gamma[c*4+3];
  float bt0 = beta[c*4+0], bt1 = beta[c*4+1], bt2 = beta[c*4+2], bt3 = beta[c*4+3];
  #pragma unroll
  for (int m = 0; m < 4; ++m){
    int n = base + r + 8*m;
    float h0 = acc[m][0] + tb0;
    float h1 = acc[m][1] + tb1;
    float h2 = acc[m][2] + tb2;
    float h3 = acc[m][3] + tb3;
    float s  = h0 + h1 + h2 + h3;
    float ss = h0*h0 + h1*h1 + h2*h2 + h3*h3;
    #pragma unroll
    for (int off = 16; off; off >>= 1){
      s  += __shfl_xor(s,  off, 32);
      ss += __shfl_xor(ss, off, 32);
    }
    float mu = s * (1.f/128.f);
    float var = ss * (1.f/128.f) - mu*mu;
    float rstd = rsqrtf(var + 1e-5f);
    if (n < NN){
      out4[n*32 + c] = make_float4((h0-mu)*rstd*gm0 + bt0,
                                   (h1-mu)*rstd*gm1 + bt1,
                                   (h2-mu)*rstd*gm2 + bt2,
                                   (h3-mu)*rstd*gm3 + bt3);
    }
  }
}

extern "C" void kernel_launch(void* const* d_in, const int* in_sizes, int n_in,
                              void* d_out, int out_size, void* d_ws, size_t ws_size,
                              hipStream_t stream){
  const float* emb          = (const float*)d_in[0];
  const int*   edges        = (const int*)d_in[1];
  const float* w_weight     = (const float*)d_in[2];
  const float* w_bias       = (const float*)d_in[3];
  const float* a_weight     = (const float*)d_in[4];
  const float* a_bias       = (const float*)d_in[5];
  const float* trans_weight = (const float*)d_in[6];
  const float* trans_bias   = (const float*)d_in[7];
  const float* ln_gamma     = (const float*)d_in[8];
  const float* ln_beta      = (const float*)d_in[9];
  float* out = (float*)d_out;

  // workspace layout
  float* ws       = (float*)d_ws;
  float* agg      = ws;                    // 6,400,000 floats (normalized agg)
  float* csr_attn = ws + 6400000;          //   800,000
  float* p1       = ws + 7200000;          //    50,000
  float* p2       = ws + 7250000;          //    50,000
  float* v12c     = ws + 7300000;          //       320 (258 used)
  int*   ibase    = (int*)(ws + 7300320);
  int*   count    = ibase;                 //    50,000
  int*   cursor   = ibase + 50000;         //    50,000
  int*   rowptr   = ibase + 100000;        //    50,001
  int*   bsum     = ibase + 150064;        //        64
  int*   boff     = ibase + 150128;        //        64
  int*   csr_src  = ibase + 150192;        //   800,000

  const int* e_dst = edges;
  const int* e_src = edges + NE;

  hipMemsetAsync(count, 0, 100000 * sizeof(int), stream);   // count + cursor
  k_prep<<<1, 128, 0, stream>>>(w_weight, w_bias, a_weight, a_bias, v12c);
  k_pvec<<<(NN + 7)/8, 256, 0, stream>>>((const float4*)emb, v12c, p1, p2);
  k_hist<<<(NE + 255)/256, 256, 0, stream>>>(e_dst, count);
  k_scanA<<<SCAN_BLK, 1024, 0, stream>>>(count, rowptr, bsum);
  k_scanB<<<1, 64, 0, stream>>>(bsum, boff);
  k_scanC<<<(NN + 255)/256, 256, 0, stream>>>(rowptr, boff);
  k_scatter<<<(NE + 255)/256, 256, 0, stream>>>(e_dst, e_src, p1, p2, rowptr, cursor,
                                                csr_src, csr_attn);
  k_gather<<<(NN + 3)/4, 256, 0, stream>>>(rowptr, csr_src, csr_attn,
                                           (const float4*)emb, (float4*)agg);
  k_out<<<(NN + 31)/32, 256, 0, stream>>>((const float4*)emb, (const float4*)agg,
                                          (const float4*)trans_weight, trans_bias,
                                          ln_gamma, ln_beta, (float4*)out);
}

// Round 3
// 269.790 us; speedup vs baseline: 5.7758x; 1.1866x over previous
//
#include <hip/hip_runtime.h>
#include <hip/hip_bf16.h>

#define NN 50000
#define NE 800000
#define DIM 128
#define SCAN_BLK 49   // ceil(50000/1024)

typedef __attribute__((ext_vector_type(8))) short short8_t;   // 8 bf16 (4 VGPRs)
typedef __attribute__((ext_vector_type(4))) float floatx4;

static __device__ inline unsigned short f2bf(float x){        // RNE float->bf16
  unsigned int u = __float_as_uint(x);
  unsigned int r = (u + 0x7FFF + ((u >> 16) & 1)) >> 16;
  return (unsigned short)r;
}
static __device__ inline float bf2f(unsigned short u){
  return __uint_as_float(((unsigned int)u) << 16);
}

// K0: fold W into attention vectors: v1 = a1^T W, v2 = a2^T W,
// c1 = b.a1 + a_bias, c2 = b.a2
__global__ void k_prep(const float* __restrict__ W, const float* __restrict__ wb,
                       const float* __restrict__ aw, const float* __restrict__ ab,
                       float* __restrict__ v12c){
  int k = threadIdx.x;                       // 0..127
  float s1 = 0.f, s2 = 0.f;
  for (int j = 0; j < DIM; ++j){
    float w = W[j*DIM + k];
    s1 += aw[j] * w;
    s2 += aw[DIM + j] * w;
  }
  v12c[k] = s1;
  v12c[DIM + k] = s2;
  __shared__ float r1[DIM], r2[DIM];
  float b = wb[k];
  r1[k] = b * aw[k];
  r2[k] = b * aw[DIM + k];
  __syncthreads();
  for (int off = 64; off > 0; off >>= 1){
    if (k < off){ r1[k] += r1[k+off]; r2[k] += r2[k+off]; }
    __syncthreads();
  }
  if (k == 0){ v12c[2*DIM] = r1[0] + ab[0]; v12c[2*DIM+1] = r2[0]; }
}

// K0b: T (f32 [128][256]) -> Tb (bf16, same layout)
__global__ __launch_bounds__(256) void k_tconv(const float4* __restrict__ T4,
                                               ushort4* __restrict__ Tb4){
  int i = blockIdx.x * 256 + threadIdx.x;    // 8192 float4s
  float4 v = T4[i];
  Tb4[i] = make_ushort4(f2bf(v.x), f2bf(v.y), f2bf(v.z), f2bf(v.w));
}

// K1: p1/p2 per node + emit bf16 emb copy + (fused) dst histogram.
__global__ __launch_bounds__(256) void k_pvec(const float4* __restrict__ emb4,
                      const float* __restrict__ v12c,
                      float* __restrict__ p1, float* __restrict__ p2,
                      unsigned short* __restrict__ embh,
                      const int* __restrict__ dst, int* __restrict__ count){
  int tid = blockIdx.x * 256 + threadIdx.x;
  if (tid < NE) atomicAdd(&count[dst[tid]], 1);    // fused histogram
  int g = threadIdx.x & 31;
  int i = blockIdx.x * 8 + (threadIdx.x >> 5);
  if (i >= NN) return;
  float4 e = emb4[i*32 + g];
  *(ushort4*)(embh + i*DIM + g*4) =
      make_ushort4(f2bf(e.x), f2bf(e.y), f2bf(e.z), f2bf(e.w));
  float4 a = ((const float4*)v12c)[g];
  float4 b = ((const float4*)v12c)[32 + g];
  float s1 = e.x*a.x + e.y*a.y + e.z*a.z + e.w*a.w;
  float s2 = e.x*b.x + e.y*b.y + e.z*b.z + e.w*b.w;
  #pragma unroll
  for (int off = 16; off; off >>= 1){
    s1 += __shfl_down(s1, off, 32);
    s2 += __shfl_down(s2, off, 32);
  }
  if (g == 0){
    p1[i] = s1 + v12c[256];
    p2[i] = s2 + v12c[257];
  }
}

// K3a: per-1024-block exclusive scan of counts; block totals to bsum
__global__ __launch_bounds__(1024) void k_scanA(const int* __restrict__ count,
                                                int* __restrict__ rowptr, int* __restrict__ bsum){
  __shared__ int sm[1024];
  int t = threadIdx.x;
  int i = blockIdx.x * 1024 + t;
  int c = (i < NN) ? count[i] : 0;
  sm[t] = c;
  __syncthreads();
  for (int off = 1; off < 1024; off <<= 1){
    int add = (t >= off) ? sm[t-off] : 0;
    __syncthreads();
    sm[t] += add;
    __syncthreads();
  }
  if (i < NN) rowptr[i] = sm[t] - c;
  if (t == 1023) bsum[blockIdx.x] = sm[t];
}

// K3b: scan the 49 block sums (single wave)
__global__ void k_scanB(const int* __restrict__ bsum, int* __restrict__ boff){
  int t = threadIdx.x;
  int v = (t < SCAN_BLK) ? bsum[t] : 0;
  int incl = v;
  #pragma unroll
  for (int off = 1; off < 64; off <<= 1){
    int u = __shfl_up(incl, off, 64);
    if (t >= off) incl += u;
  }
  if (t < SCAN_BLK) boff[t] = incl - v;
}

// K3c: add block offsets; set rowptr[NN]
__global__ __launch_bounds__(256) void k_scanC(int* __restrict__ rowptr, const int* __restrict__ boff){
  int i = blockIdx.x * 256 + threadIdx.x;
  if (i < NN) rowptr[i] += boff[i >> 10];
  if (i == 0) rowptr[NN] = NE;
}

// K4: scatter edges into CSR order (packed int2 {src, attn-bits}).
// Cursor = atomicSub on the (still-populated) count array.
__global__ __launch_bounds__(256) void k_scatter(const int* __restrict__ dst, const int* __restrict__ src,
                        const float* __restrict__ p1, const float* __restrict__ p2,
                        const int* __restrict__ rowptr, int* __restrict__ count,
                        int2* __restrict__ csr){
  int e = blockIdx.x * 256 + threadIdx.x;
  if (e >= NE) return;
  int d = dst[e];
  int s = src[e];
  float sc = p1[d] + p2[s];                 // a_bias folded into p1
  sc = sc > 0.f ? sc : 0.2f * sc;
  float a = __expf(sc);
  int pos = rowptr[d] + atomicSub(&count[d], 1) - 1;
  csr[pos] = make_int2(s, __float_as_int(a));
}

// K5: one 64-lane wave per destination; bf16 row gathers (256B/edge),
// accumulate fp32 in registers, normalize in-wave, store bf16 agg row.
__global__ __launch_bounds__(256) void k_gather(const int* __restrict__ rowptr,
                       const int2* __restrict__ csr,
                       const unsigned short* __restrict__ embh,
                       unsigned short* __restrict__ aggh){
  int lane = threadIdx.x & 63;
  int g = lane & 31;
  int h = lane >> 5;
  int n = blockIdx.x * 4 + (threadIdx.x >> 6);
  if (n >= NN) return;
  int s0 = rowptr[n], s1 = rowptr[n+1];
  float4 acc = make_float4(0.f, 0.f, 0.f, 0.f);
  float dsum = 0.f;
  for (int e = s0 + h; e < s1; e += 2){
    int2 ea = csr[e];                       // coalesced 8B
    float a = __int_as_float(ea.y);
    dsum += a;
    ushort4 v = *(const ushort4*)(embh + ea.x*DIM + g*4);   // 256B/half-wave
    acc.x += a * bf2f(v.x); acc.y += a * bf2f(v.y);
    acc.z += a * bf2f(v.z); acc.w += a * bf2f(v.w);
  }
  acc.x += __shfl_xor(acc.x, 32, 64);
  acc.y += __shfl_xor(acc.y, 32, 64);
  acc.z += __shfl_xor(acc.z, 32, 64);
  acc.w += __shfl_xor(acc.w, 32, 64);
  dsum  += __shfl_xor(dsum, 32, 64);
  if (h == 0){
    float dinv = 1.0f / (dsum + 1e-20f);
    *(ushort4*)(aggh + n*DIM + g*4) =
        make_ushort4(f2bf(acc.x*dinv), f2bf(acc.y*dinv),
                     f2bf(acc.z*dinv), f2bf(acc.w*dinv));
  }
}

// K6: MFMA GEMM h = [embh|aggh] @ Tb^T + tb, fused LayerNorm.
// Block = 4 waves x 16 nodes = 64 nodes; wave: 16 nodes x 128 cols,
// K=256 in 8 chunks of 32. Barrier-free: A/B frags loaded direct from global.
__global__ __launch_bounds__(256) void k_out(const unsigned short* __restrict__ embh,
                     const unsigned short* __restrict__ aggh,
                     const unsigned short* __restrict__ Tb,
                     const float* __restrict__ tb,
                     const float* __restrict__ gamma, const float* __restrict__ beta,
                     float* __restrict__ out){
  int t = threadIdx.x;
  int w = t >> 6;
  int lane = t & 63;
  int m16 = lane & 15;
  int q = lane >> 4;                         // 0..3
  int nodebase = blockIdx.x * 64 + w * 16;
  int nA = nodebase + m16;
  int nAc = (nA < NN) ? nA : 0;              // clamp loads; stores guarded
  floatx4 acc[8];
  #pragma unroll
  for (int ct = 0; ct < 8; ++ct) acc[ct] = (floatx4){0.f, 0.f, 0.f, 0.f};

  #pragma unroll
  for (int kc = 0; kc < 8; ++kc){
    int k0 = kc*32 + q*8;
    const unsigned short* aptr = (kc < 4) ? (embh + nAc*DIM + k0)
                                          : (aggh + nAc*DIM + (k0 - 128));
    short8_t afrag = *(const short8_t*)aptr;           // A[m=m16][k0..k0+7]
    #pragma unroll
    for (int ct = 0; ct < 8; ++ct){
      short8_t bfrag = *(const short8_t*)(Tb + (ct*16 + m16)*256 + k0); // B[k][j]=T[j][k]
      acc[ct] = __builtin_amdgcn_mfma_f32_16x16x32_bf16(afrag, bfrag, acc[ct], 0, 0, 0);
    }
  }

  float tbv[8], gmv[8], btv[8];
  #pragma unroll
  for (int ct = 0; ct < 8; ++ct){
    int col = ct*16 + m16;
    tbv[ct] = tb[col]; gmv[ct] = gamma[col]; btv[ct] = beta[col];
  }
  #pragma unroll
  for (int r = 0; r < 4; ++r){
    int n = nodebase + q*4 + r;              // D row = q*4 + reg
    float h[8]; float s = 0.f, ss = 0.f;
    #pragma unroll
    for (int ct = 0; ct < 8; ++ct){
      h[ct] = acc[ct][r] + tbv[ct];
      s += h[ct]; ss += h[ct]*h[ct];
    }
    #pragma unroll
    for (int off = 1; off < 16; off <<= 1){  // reduce across the 16 lanes of group q
      s  += __shfl_xor(s,  off, 16);
      ss += __shfl_xor(ss, off, 16);
    }
    float mu = s * (1.f/128.f);
    float var = ss * (1.f/128.f) - mu*mu;
    float rstd = rsqrtf(var + 1e-5f);
    if (n < NN){
      #pragma unroll
      for (int ct = 0; ct < 8; ++ct){
        out[n*DIM + ct*16 + m16] = (h[ct]-mu)*rstd*gmv[ct] + btv[ct];
      }
    }
  }
}

extern "C" void kernel_launch(void* const* d_in, const int* in_sizes, int n_in,
                              void* d_out, int out_size, void* d_ws, size_t ws_size,
                              hipStream_t stream){
  const float* emb          = (const float*)d_in[0];
  const int*   edges        = (const int*)d_in[1];
  const float* w_weight     = (const float*)d_in[2];
  const float* w_bias       = (const float*)d_in[3];
  const float* a_weight     = (const float*)d_in[4];
  const float* a_bias       = (const float*)d_in[5];
  const float* trans_weight = (const float*)d_in[6];
  const float* trans_bias   = (const float*)d_in[7];
  const float* ln_gamma     = (const float*)d_in[8];
  const float* ln_beta      = (const float*)d_in[9];
  float* out = (float*)d_out;

  // ws layout (float offsets):
  // p1[50k] p2[50k] v12c[320] | ints: count[50k] rowptr[50064] bsum[64] boff[64]
  // | csr int2[800k] | embh bf16[6.4M] | aggh bf16[6.4M] | Tb bf16[32768]
  float* ws     = (float*)d_ws;
  float* p1     = ws;
  float* p2     = ws + 50000;
  float* v12c   = ws + 100000;
  int*   ibase  = (int*)(ws + 100320);
  int*   count  = ibase;
  int*   rowptr = ibase + 50000;
  int*   bsum   = ibase + 100064;
  int*   boff   = ibase + 100128;
  int2*  csr    = (int2*)(ws + 200512);
  unsigned short* embh = (unsigned short*)(ws + 1800512);
  unsigned short* aggh = (unsigned short*)(ws + 5000512);
  unsigned short* Tb   = (unsigned short*)(ws + 8200512);

  const int* e_dst = edges;
  const int* e_src = edges + NE;

  hipMemsetAsync(count, 0, 50000 * sizeof(int), stream);
  k_prep<<<1, 128, 0, stream>>>(w_weight, w_bias, a_weight, a_bias, v12c);
  k_tconv<<<32, 256, 0, stream>>>((const float4*)trans_weight, (ushort4*)Tb);
  k_pvec<<<(NN + 7)/8, 256, 0, stream>>>((const float4*)emb, v12c, p1, p2,
                                         embh, e_dst, count);
  k_scanA<<<SCAN_BLK, 1024, 0, stream>>>(count, rowptr, bsum);
  k_scanB<<<1, 64, 0, stream>>>(bsum, boff);
  k_scanC<<<(NN + 255)/256, 256, 0, stream>>>(rowptr, boff);
  k_scatter<<<(NE + 255)/256, 256, 0, stream>>>(e_dst, e_src, p1, p2, rowptr, count, csr);
  k_gather<<<(NN + 3)/4, 256, 0, stream>>>(rowptr, csr, embh, aggh);
  k_out<<<(NN + 63)/64, 256, 0, stream>>>(embh, aggh, Tb, trans_bias,
                                          ln_gamma, ln_beta, out);
}

// Round 4
// 222.381 us; speedup vs baseline: 7.0071x; 1.2132x over previous
//
#include <hip/hip_runtime.h>
#include <hip/hip_bf16.h>

#define NN 50000
#define NE 800000
#define DIM 128
#define SCAN_BLK 49   // ceil(50000/1024)

typedef __attribute__((ext_vector_type(8))) short short8_t;           // 8 bf16 for MFMA
typedef __attribute__((ext_vector_type(8))) unsigned short ushort8_t; // 8 bf16 raw
typedef __attribute__((ext_vector_type(4))) float floatx4;

static __device__ inline unsigned short f2bf(float x){        // RNE float->bf16
  unsigned int u = __float_as_uint(x);
  unsigned int r = (u + 0x7FFF + ((u >> 16) & 1)) >> 16;
  return (unsigned short)r;
}
static __device__ inline float bf2f(unsigned short u){
  return __uint_as_float(((unsigned int)u) << 16);
}

// K0: heterogeneous setup. Block 0: fold W into attention vectors
// (v1 = a1^T W, v2 = a2^T W, c1 = b.a1 + a_bias, c2 = b.a2).
// Blocks 1..32: T f32 -> bf16. Blocks 33..228: zero count.
__global__ __launch_bounds__(256) void k_setup(const float* __restrict__ W,
                       const float* __restrict__ wb,
                       const float* __restrict__ aw, const float* __restrict__ ab,
                       float* __restrict__ v12c,
                       const float4* __restrict__ T4, ushort4* __restrict__ Tb4,
                       int* __restrict__ count){
  int b = blockIdx.x;
  int t = threadIdx.x;
  if (b == 0){
    __shared__ float r1[DIM], r2[DIM];
    if (t < DIM){
      float s1 = 0.f, s2 = 0.f;
      for (int j = 0; j < DIM; ++j){
        float w = W[j*DIM + t];
        s1 += aw[j] * w;
        s2 += aw[DIM + j] * w;
      }
      v12c[t] = s1;
      v12c[DIM + t] = s2;
      float bb = wb[t];
      r1[t] = bb * aw[t];
      r2[t] = bb * aw[DIM + t];
    }
    __syncthreads();
    if (t == 0){
      float a1s = 0.f, a2s = 0.f;
      for (int j = 0; j < DIM; ++j){ a1s += r1[j]; a2s += r2[j]; }
      v12c[2*DIM]   = a1s + ab[0];
      v12c[2*DIM+1] = a2s;
    }
  } else if (b <= 32){
    int i = (b-1)*256 + t;              // 8192 float4s of T
    float4 v = T4[i];
    Tb4[i] = make_ushort4(f2bf(v.x), f2bf(v.y), f2bf(v.z), f2bf(v.w));
  } else {
    int i = (b-33)*256 + t;
    if (i < NN) count[i] = 0;
  }
}

// K1: p1/p2 per node + bf16 emb copy + fused histogram whose atomicAdd
// RETURN VALUE is stored as the edge's within-row rank (kills scatter atomics).
__global__ __launch_bounds__(256) void k_pvec(const float4* __restrict__ emb4,
                      const float* __restrict__ v12c,
                      float* __restrict__ p1, float* __restrict__ p2,
                      unsigned short* __restrict__ embh,
                      const int* __restrict__ dst, int* __restrict__ count,
                      int* __restrict__ rank){
  int tid = blockIdx.x * 256 + threadIdx.x;
  if (tid < NE) rank[tid] = atomicAdd(&count[dst[tid]], 1);
  int g = threadIdx.x & 31;
  int i = blockIdx.x * 8 + (threadIdx.x >> 5);
  if (i >= NN) return;
  float4 e = emb4[i*32 + g];
  *(ushort4*)(embh + i*DIM + g*4) =
      make_ushort4(f2bf(e.x), f2bf(e.y), f2bf(e.z), f2bf(e.w));
  float4 a = ((const float4*)v12c)[g];
  float4 b = ((const float4*)v12c)[32 + g];
  float s1 = e.x*a.x + e.y*a.y + e.z*a.z + e.w*a.w;
  float s2 = e.x*b.x + e.y*b.y + e.z*b.z + e.w*b.w;
  #pragma unroll
  for (int off = 16; off; off >>= 1){
    s1 += __shfl_down(s1, off, 32);
    s2 += __shfl_down(s2, off, 32);
  }
  if (g == 0){
    p1[i] = s1 + v12c[256];
    p2[i] = s2 + v12c[257];
  }
}

// K2: block-level exclusive scan (shuffle-based, 2 barriers), block totals -> bsum
__global__ __launch_bounds__(1024) void k_scanA(const int* __restrict__ count,
                                                int* __restrict__ rowptr,
                                                int* __restrict__ bsum){
  __shared__ int wsum[16];
  int t = threadIdx.x;
  int i = blockIdx.x * 1024 + t;
  int v = (i < NN) ? count[i] : 0;
  int incl = v;
  int lane = t & 63;
  #pragma unroll
  for (int off = 1; off < 64; off <<= 1){
    int u = __shfl_up(incl, off, 64);
    if (lane >= off) incl += u;
  }
  int wid = t >> 6;
  if (lane == 63) wsum[wid] = incl;
  __syncthreads();
  if (t < 64){
    int x = (t < 16) ? wsum[t] : 0;
    int xi = x;
    #pragma unroll
    for (int off = 1; off < 16; off <<= 1){
      int u = __shfl_up(xi, off, 64);
      if (t >= off) xi += u;
    }
    if (t < 16) wsum[t] = xi - x;        // exclusive wave offsets
  }
  __syncthreads();
  int excl = incl - v + wsum[wid];
  if (i < NN) rowptr[i] = excl;
  if (t == 1023) bsum[blockIdx.x] = excl + v;
}

// K3: fused scanB+C — every block redundantly wave-scans the 49 block sums,
// then adds the offset to its rowptr slice.
__global__ __launch_bounds__(256) void k_scanBC(int* __restrict__ rowptr,
                                                const int* __restrict__ bsum){
  __shared__ int boff[64];
  int t = threadIdx.x;
  if (t < 64){
    int v = (t < SCAN_BLK) ? bsum[t] : 0;
    int incl = v;
    #pragma unroll
    for (int off = 1; off < 64; off <<= 1){
      int u = __shfl_up(incl, off, 64);
      if (t >= off) incl += u;
    }
    boff[t] = incl - v;
  }
  __syncthreads();
  int i = blockIdx.x * 256 + t;
  if (i < NN) rowptr[i] += boff[i >> 10];
  if (i == 0) rowptr[NN] = NE;
}

// K4: atomic-free scatter: pos = rowptr[d] + rank[e]; one random 4B store.
__global__ __launch_bounds__(256) void k_scatter(const int* __restrict__ dst,
                        const int* __restrict__ src, const int* __restrict__ rank,
                        const int* __restrict__ rowptr, int* __restrict__ csr_src){
  int e = blockIdx.x * 256 + threadIdx.x;
  if (e >= NE) return;
  int d = dst[e];
  csr_src[rowptr[d] + rank[e]] = src[e];
}

// K5: one 64-lane wave per destination node, 4 edges in flight
// (16 lanes x 16B = one 256B bf16 row each). attn computed inline
// (p2[s] is an L2-resident broadcast read). fp32 accum, bf16 row store.
__global__ __launch_bounds__(256) void k_gather(const int* __restrict__ rowptr,
                       const int* __restrict__ csr_src,
                       const float* __restrict__ p1, const float* __restrict__ p2,
                       const unsigned short* __restrict__ embh,
                       unsigned short* __restrict__ aggh){
  int lane = threadIdx.x & 63;
  int c16 = lane & 15;                 // column slot (8 bf16 each)
  int g4 = lane >> 4;                  // edge slot 0..3
  int n = blockIdx.x * 4 + (threadIdx.x >> 6);
  if (n >= NN) return;
  int s0 = rowptr[n], s1 = rowptr[n+1];
  float p1n = p1[n];
  float acc[8] = {0.f,0.f,0.f,0.f,0.f,0.f,0.f,0.f};
  float dsum = 0.f;
  for (int e = s0 + g4; e < s1; e += 4){
    int s = csr_src[e];                              // broadcast per 16-lane group
    float sc = p1n + p2[s];                          // L2-resident (200 KB)
    sc = sc > 0.f ? sc : 0.2f * sc;
    float a = __expf(sc);
    dsum += a;
    ushort8_t v = *(const ushort8_t*)(embh + s*DIM + c16*8);  // 256B/group
    #pragma unroll
    for (int j = 0; j < 8; ++j) acc[j] += a * bf2f(v[j]);
  }
  #pragma unroll
  for (int j = 0; j < 8; ++j){
    acc[j] += __shfl_xor(acc[j], 16, 64);
    acc[j] += __shfl_xor(acc[j], 32, 64);
  }
  dsum += __shfl_xor(dsum, 16, 64);
  dsum += __shfl_xor(dsum, 32, 64);
  if (g4 == 0){
    float dinv = 1.0f / (dsum + 1e-20f);
    ushort8_t o;
    #pragma unroll
    for (int j = 0; j < 8; ++j) o[j] = f2bf(acc[j] * dinv);
    *(ushort8_t*)(aggh + n*DIM + c16*8) = o;
  }
}

// K6: MFMA GEMM h = [embh|aggh] @ Tb^T + tb, fused LayerNorm.
// Block = 4 waves x 16 nodes; barrier-free, B frags L2-broadcast.
__global__ __launch_bounds__(256) void k_out(const unsigned short* __restrict__ embh,
                     const unsigned short* __restrict__ aggh,
                     const unsigned short* __restrict__ Tb,
                     const float* __restrict__ tb,
                     const float* __restrict__ gamma, const float* __restrict__ beta,
                     float* __restrict__ out){
  int t = threadIdx.x;
  int w = t >> 6;
  int lane = t & 63;
  int m16 = lane & 15;
  int q = lane >> 4;                         // 0..3
  int nodebase = blockIdx.x * 64 + w * 16;
  int nA = nodebase + m16;
  int nAc = (nA < NN) ? nA : 0;              // clamp loads; stores guarded
  floatx4 acc[8];
  #pragma unroll
  for (int ct = 0; ct < 8; ++ct) acc[ct] = (floatx4){0.f, 0.f, 0.f, 0.f};

  #pragma unroll
  for (int kc = 0; kc < 8; ++kc){
    int k0 = kc*32 + q*8;
    const unsigned short* aptr = (kc < 4) ? (embh + nAc*DIM + k0)
                                          : (aggh + nAc*DIM + (k0 - 128));
    short8_t afrag = *(const short8_t*)aptr;           // A[m=m16][k0..k0+7]
    #pragma unroll
    for (int ct = 0; ct < 8; ++ct){
      short8_t bfrag = *(const short8_t*)(Tb + (ct*16 + m16)*256 + k0); // B[k][j]=T[j][k]
      acc[ct] = __builtin_amdgcn_mfma_f32_16x16x32_bf16(afrag, bfrag, acc[ct], 0, 0, 0);
    }
  }

  float tbv[8], gmv[8], btv[8];
  #pragma unroll
  for (int ct = 0; ct < 8; ++ct){
    int col = ct*16 + m16;
    tbv[ct] = tb[col]; gmv[ct] = gamma[col]; btv[ct] = beta[col];
  }
  #pragma unroll
  for (int r = 0; r < 4; ++r){
    int n = nodebase + q*4 + r;              // D row = q*4 + reg
    float h[8]; float s = 0.f, ss = 0.f;
    #pragma unroll
    for (int ct = 0; ct < 8; ++ct){
      h[ct] = acc[ct][r] + tbv[ct];
      s += h[ct]; ss += h[ct]*h[ct];
    }
    #pragma unroll
    for (int off = 1; off < 16; off <<= 1){
      s  += __shfl_xor(s,  off, 16);
      ss += __shfl_xor(ss, off, 16);
    }
    float mu = s * (1.f/128.f);
    float var = ss * (1.f/128.f) - mu*mu;
    float rstd = rsqrtf(var + 1e-5f);
    if (n < NN){
      #pragma unroll
      for (int ct = 0; ct < 8; ++ct){
        out[n*DIM + ct*16 + m16] = (h[ct]-mu)*rstd*gmv[ct] + btv[ct];
      }
    }
  }
}

extern "C" void kernel_launch(void* const* d_in, const int* in_sizes, int n_in,
                              void* d_out, int out_size, void* d_ws, size_t ws_size,
                              hipStream_t stream){
  const float* emb          = (const float*)d_in[0];
  const int*   edges        = (const int*)d_in[1];
  const float* w_weight     = (const float*)d_in[2];
  const float* w_bias       = (const float*)d_in[3];
  const float* a_weight     = (const float*)d_in[4];
  const float* a_bias       = (const float*)d_in[5];
  const float* trans_weight = (const float*)d_in[6];
  const float* trans_bias   = (const float*)d_in[7];
  const float* ln_gamma     = (const float*)d_in[8];
  const float* ln_beta      = (const float*)d_in[9];
  float* out = (float*)d_out;

  // ws layout (float offsets):
  // p1[50k] p2[50k] v12c[320] | ints: count[50k] rowptr[50064] bsum[64]
  //   rank[800k] csr_src[800k] | embh bf16[6.4M] | aggh bf16[6.4M] | Tb bf16[32768]
  float* ws      = (float*)d_ws;
  float* p1      = ws;
  float* p2      = ws + 50000;
  float* v12c    = ws + 100000;
  int*   ibase   = (int*)(ws + 100320);
  int*   count   = ibase;
  int*   rowptr  = ibase + 50000;
  int*   bsum    = ibase + 100064;
  int*   rank    = ibase + 100128;
  int*   csr_src = ibase + 900128;
  unsigned short* embh = (unsigned short*)(ws + 1800448);
  unsigned short* aggh = (unsigned short*)(ws + 5000448);
  unsigned short* Tb   = (unsigned short*)(ws + 8200448);

  const int* e_dst = edges;
  const int* e_src = edges + NE;

  k_setup<<<229, 256, 0, stream>>>(w_weight, w_bias, a_weight, a_bias, v12c,
                                   (const float4*)trans_weight, (ushort4*)Tb, count);
  k_pvec<<<(NN + 7)/8, 256, 0, stream>>>((const float4*)emb, v12c, p1, p2,
                                         embh, e_dst, count, rank);
  k_scanA<<<SCAN_BLK, 1024, 0, stream>>>(count, rowptr, bsum);
  k_scanBC<<<(NN + 255)/256, 256, 0, stream>>>(rowptr, bsum);
  k_scatter<<<(NE + 255)/256, 256, 0, stream>>>(e_dst, e_src, rank, rowptr, csr_src);
  k_gather<<<(NN + 3)/4, 256, 0, stream>>>(rowptr, csr_src, p1, p2, embh, aggh);
  k_out<<<(NN + 63)/64, 256, 0, stream>>>(embh, aggh, Tb, trans_bias,
                                          ln_gamma, ln_beta, out);
}